// Round 1
// baseline (268.876 us; speedup 1.0000x reference)
//
#include <hip/hip_runtime.h>
#include <hip/hip_bf16.h>

typedef float f32x4 __attribute__((ext_vector_type(4)));
typedef short bf16x8 __attribute__((ext_vector_type(8)));

#define NSEQ 2048
#define CDIM 1024
#define NHEAD 16
#define HDIM 64
#define MROWS 4096

__device__ __forceinline__ unsigned short f2bf(float f) {
    unsigned int u = __builtin_bit_cast(unsigned int, f);
    u += 0x7FFFu + ((u >> 16) & 1u);
    return (unsigned short)(u >> 16);
}

// ---------------- f32 -> bf16 conversion (memory-bound) ----------------
__global__ __launch_bounds__(256) void cvt_bf16_kernel(const float* __restrict__ src,
                                                       unsigned short* __restrict__ dst,
                                                       int n) {
    int i = (blockIdx.x * 256 + threadIdx.x) * 4;
    if (i < n) {
        float4 v = *reinterpret_cast<const float4*>(src + i);
        ushort4 o;
        o.x = f2bf(v.x); o.y = f2bf(v.y); o.z = f2bf(v.z); o.w = f2bf(v.w);
        *reinterpret_cast<ushort4*>(dst + i) = o;
    }
}

// ---------------- fused projection GEMM + bias + RoPE -------------------
// out[m,j] = sum_c X[m,c] * W[j,c] + b[j]; z=0:Q(rope) z=1:K(rope) z=2:V(->V^T layout)
// grid (8, 32, 3), block 256 (4 waves, 2x2 wave grid, 64x64 per wave)
__global__ __launch_bounds__(256) void gemm_rope_kernel(
    const unsigned short* __restrict__ Xq, const unsigned short* __restrict__ Xk,
    const unsigned short* __restrict__ Xv,
    const unsigned short* __restrict__ Wqb, const unsigned short* __restrict__ Wkb,
    const unsigned short* __restrict__ Wvb,
    const float* __restrict__ bq, const float* __restrict__ bk, const float* __restrict__ bv,
    const float* __restrict__ qcos, const float* __restrict__ qsin,
    const float* __restrict__ kcos, const float* __restrict__ ksin,
    unsigned short* __restrict__ Qh, unsigned short* __restrict__ Kh,
    unsigned short* __restrict__ VT)
{
    __shared__ unsigned short Al[128][72];   // padded: stride 144B -> ~2-way (free)
    __shared__ unsigned short Bl[128][72];

    const int tid  = threadIdx.x;
    const int wave = tid >> 6;
    const int lane = tid & 63;
    const int lr   = lane & 15;
    const int lg   = lane >> 4;
    const int lk   = lg * 8;
    const int wm   = wave >> 1;
    const int wn   = wave & 1;
    const int m0   = blockIdx.y * 128;
    const int j0   = blockIdx.x * 128;
    const int z    = blockIdx.z;

    const unsigned short* X = (z == 0) ? Xq : (z == 1) ? Xk : Xv;
    const unsigned short* W = (z == 0) ? Wqb : (z == 1) ? Wkb : Wvb;
    const float* bias = (z == 0) ? bq : (z == 1) ? bk : bv;
    const float* cosb = (z == 0) ? qcos : kcos;
    const float* sinb = (z == 0) ? qsin : ksin;

    f32x4 acc[4][4];
    const f32x4 zero4 = {0.f, 0.f, 0.f, 0.f};
    #pragma unroll
    for (int a = 0; a < 4; a++)
        #pragma unroll
        for (int b = 0; b < 4; b++) acc[a][b] = zero4;

    for (int k0 = 0; k0 < CDIM; k0 += 64) {
        __syncthreads();
        #pragma unroll
        for (int it = 0; it < 4; it++) {
            int c = tid + it * 256;          // 1024 chunks of 8 bf16
            int row = c >> 3, col = (c & 7) << 3;
            *reinterpret_cast<bf16x8*>(&Al[row][col]) =
                *reinterpret_cast<const bf16x8*>(X + (size_t)(m0 + row) * CDIM + k0 + col);
            *reinterpret_cast<bf16x8*>(&Bl[row][col]) =
                *reinterpret_cast<const bf16x8*>(W + (size_t)(j0 + row) * CDIM + k0 + col);
        }
        __syncthreads();
        #pragma unroll
        for (int ks = 0; ks < 2; ks++) {
            bf16x8 af[4], bfm[4];
            #pragma unroll
            for (int mi = 0; mi < 4; mi++)
                af[mi] = *reinterpret_cast<const bf16x8*>(&Al[wm * 64 + 16 * mi + lr][ks * 32 + lk]);
            #pragma unroll
            for (int ni = 0; ni < 4; ni++)
                bfm[ni] = *reinterpret_cast<const bf16x8*>(&Bl[wn * 64 + 16 * ni + lr][ks * 32 + lk]);
            #pragma unroll
            for (int mi = 0; mi < 4; mi++)
                #pragma unroll
                for (int ni = 0; ni < 4; ni++)
                    acc[mi][ni] = __builtin_amdgcn_mfma_f32_16x16x32_bf16(
                        af[mi], bfm[ni], acc[mi][ni], 0, 0, 0);
        }
    }

    // epilogue: bias (+ rope for Q/K), scatter to [B,H,N,hd] (Q,K) or [B,H,hd,N] (V^T)
    #pragma unroll
    for (int mi = 0; mi < 4; mi++) {
        const int mbase = m0 + wm * 64 + 16 * mi + 4 * lg;   // + r
        #pragma unroll
        for (int ni = 0; ni < 4; ni++) {
            const int j  = j0 + wn * 64 + 16 * ni + lr;
            const float bj = bias[j];
            if (z == 2) {
                const int b = mbase >> 11, n = mbase & 2047;
                const int h = j >> 6, d = j & 63;
                ushort4 pk;
                pk.x = f2bf(acc[mi][ni][0] + bj);
                pk.y = f2bf(acc[mi][ni][1] + bj);
                pk.z = f2bf(acc[mi][ni][2] + bj);
                pk.w = f2bf(acc[mi][ni][3] + bj);
                *reinterpret_cast<ushort4*>(VT + ((size_t)((b * NHEAD + h) * HDIM + d) << 11) + n) = pk;
            } else {
                unsigned short* Out = (z == 0) ? Qh : Kh;
                const int hi = (j & 63) >> 1;
                const float sg = (j & 1) ? 1.f : -1.f;   // even col: -sin, odd col: +sin
                float vv[4], pp[4];
                #pragma unroll
                for (int r = 0; r < 4; r++) vv[r] = acc[mi][ni][r] + bj;
                #pragma unroll
                for (int r = 0; r < 4; r++) pp[r] = __shfl_xor(vv[r], 1);
                #pragma unroll
                for (int r = 0; r < 4; r++) {
                    const int m = mbase + r;
                    const int b = m >> 11, n = m & 2047;
                    const float c = cosb[n * 32 + hi];
                    const float s = sinb[n * 32 + hi];
                    const float ov = fmaf(vv[r], c, pp[r] * (sg * s));
                    Out[((size_t)((b * NHEAD + (j >> 6)) * NSEQ + n) << 6) + (j & 63)] = f2bf(ov);
                }
            }
        }
    }
}

// ---------------- flash attention -------------------
// grid (16, 32): x = q-tile of 128 rows, y = b*H + h. block 256 = 4 waves,
// wave w owns q rows [q0+w*32, +32). KV tiles of 64. Online softmax per wave.
__global__ __launch_bounds__(256) void attn_kernel(
    const unsigned short* __restrict__ Qh, const unsigned short* __restrict__ Kh,
    const unsigned short* __restrict__ VT, float* __restrict__ out)
{
    __shared__ unsigned short Kl[64][72];
    __shared__ unsigned short Vl[64][72];        // V^T tile: [d][kk]
    __shared__ unsigned short Pl[4][32][72];     // per-wave P

    const int tid  = threadIdx.x;
    const int wave = tid >> 6;
    const int lane = tid & 63;
    const int lr   = lane & 15;
    const int lg   = lane >> 4;
    const int bh   = blockIdx.y;
    const int q0   = blockIdx.x * 128 + wave * 32;

    const unsigned short* Qb = Qh + (size_t)bh * NSEQ * HDIM;
    const unsigned short* Kb = Kh + (size_t)bh * NSEQ * HDIM;
    const unsigned short* Vb = VT + (size_t)bh * HDIM * NSEQ;

    // Q fragments held in registers for the whole kernel
    bf16x8 qf[2][2];
    #pragma unroll
    for (int mi = 0; mi < 2; mi++)
        #pragma unroll
        for (int ks = 0; ks < 2; ks++)
            qf[mi][ks] = *reinterpret_cast<const bf16x8*>(
                Qb + (size_t)(q0 + 16 * mi + lr) * HDIM + ks * 32 + lg * 8);

    const f32x4 zero4 = {0.f, 0.f, 0.f, 0.f};
    f32x4 o[2][4];
    float mrun[2][4], lrun[2][4];
    #pragma unroll
    for (int mi = 0; mi < 2; mi++) {
        #pragma unroll
        for (int ni = 0; ni < 4; ni++) o[mi][ni] = zero4;
        #pragma unroll
        for (int r = 0; r < 4; r++) { mrun[mi][r] = -1e30f; lrun[mi][r] = 0.f; }
    }

    const float kscale = 0.125f * 1.4426950408889634f;  // scale * log2(e)

    for (int t = 0; t < 32; t++) {
        const int n0 = t * 64;
        __syncthreads();   // prev-iter PV/S reads of Kl/Vl done
        #pragma unroll
        for (int it = 0; it < 2; it++) {
            int c = tid + it * 256;            // 512 chunks of 8 bf16
            int row = c >> 3, col = (c & 7) << 3;
            *reinterpret_cast<bf16x8*>(&Kl[row][col]) =
                *reinterpret_cast<const bf16x8*>(Kb + (size_t)(n0 + row) * HDIM + col);
            *reinterpret_cast<bf16x8*>(&Vl[row][col]) =
                *reinterpret_cast<const bf16x8*>(Vb + (size_t)row * NSEQ + n0 + col);
        }
        __syncthreads();

        // S = Q K^T   (32 q-rows x 64 keys per wave)
        f32x4 s[2][4];
        #pragma unroll
        for (int mi = 0; mi < 2; mi++)
            #pragma unroll
            for (int ni = 0; ni < 4; ni++) s[mi][ni] = zero4;
        #pragma unroll
        for (int ks = 0; ks < 2; ks++) {
            bf16x8 kf[4];
            #pragma unroll
            for (int ni = 0; ni < 4; ni++)
                kf[ni] = *reinterpret_cast<const bf16x8*>(&Kl[16 * ni + lr][ks * 32 + lg * 8]);
            #pragma unroll
            for (int mi = 0; mi < 2; mi++)
                #pragma unroll
                for (int ni = 0; ni < 4; ni++)
                    s[mi][ni] = __builtin_amdgcn_mfma_f32_16x16x32_bf16(
                        qf[mi][ks], kf[ni], s[mi][ni], 0, 0, 0);
        }

        // online softmax (rows owned by 16-lane groups; reduce over lanes 0..15)
        #pragma unroll
        for (int mi = 0; mi < 2; mi++) {
            #pragma unroll
            for (int r = 0; r < 4; r++) {
                float tm = fmaxf(fmaxf(s[mi][0][r], s[mi][1][r]),
                                 fmaxf(s[mi][2][r], s[mi][3][r]));
                tm = fmaxf(tm, __shfl_xor(tm, 1));
                tm = fmaxf(tm, __shfl_xor(tm, 2));
                tm = fmaxf(tm, __shfl_xor(tm, 4));
                tm = fmaxf(tm, __shfl_xor(tm, 8));
                const float mnew  = fmaxf(mrun[mi][r], tm);
                const float alpha = exp2f((mrun[mi][r] - mnew) * kscale);
                mrun[mi][r] = mnew;
                float rs = 0.f;
                #pragma unroll
                for (int ni = 0; ni < 4; ni++) {
                    float p = exp2f((s[mi][ni][r] - mnew) * kscale);
                    s[mi][ni][r] = p;
                    rs += p;
                }
                rs += __shfl_xor(rs, 1);
                rs += __shfl_xor(rs, 2);
                rs += __shfl_xor(rs, 4);
                rs += __shfl_xor(rs, 8);
                lrun[mi][r] = lrun[mi][r] * alpha + rs;
                #pragma unroll
                for (int ni = 0; ni < 4; ni++) o[mi][ni][r] *= alpha;
            }
        }

        // P -> LDS (acc layout -> A-frag layout via LDS round trip)
        #pragma unroll
        for (int mi = 0; mi < 2; mi++)
            #pragma unroll
            for (int ni = 0; ni < 4; ni++)
                #pragma unroll
                for (int r = 0; r < 4; r++)
                    Pl[wave][16 * mi + 4 * lg + r][16 * ni + lr] = f2bf(s[mi][ni][r]);
        __syncthreads();   // ordering fence for intra-wave cross-lane LDS reuse

        // O += P V
        #pragma unroll
        for (int ks = 0; ks < 2; ks++) {
            bf16x8 pf[2], vf[4];
            #pragma unroll
            for (int mi = 0; mi < 2; mi++)
                pf[mi] = *reinterpret_cast<const bf16x8*>(&Pl[wave][16 * mi + lr][ks * 32 + lg * 8]);
            #pragma unroll
            for (int ni = 0; ni < 4; ni++)
                vf[ni] = *reinterpret_cast<const bf16x8*>(&Vl[16 * ni + lr][ks * 32 + lg * 8]);
            #pragma unroll
            for (int mi = 0; mi < 2; mi++)
                #pragma unroll
                for (int ni = 0; ni < 4; ni++)
                    o[mi][ni] = __builtin_amdgcn_mfma_f32_16x16x32_bf16(
                        pf[mi], vf[ni], o[mi][ni], 0, 0, 0);
        }
    }

    // epilogue: normalize, write [B,N,C] f32
    const int b = bh >> 4, h = bh & 15;
    #pragma unroll
    for (int mi = 0; mi < 2; mi++)
        #pragma unroll
        for (int ni = 0; ni < 4; ni++)
            #pragma unroll
            for (int r = 0; r < 4; r++) {
                const int n = q0 + 16 * mi + 4 * lg + r;
                const int d = 16 * ni + lr;
                out[((size_t)(b * NSEQ + n) << 10) + h * HDIM + d] = o[mi][ni][r] / lrun[mi][r];
            }
}

extern "C" void kernel_launch(void* const* d_in, const int* in_sizes, int n_in,
                              void* d_out, int out_size, void* d_ws, size_t ws_size,
                              hipStream_t stream) {
    const float* q    = (const float*)d_in[0];
    const float* k    = (const float*)d_in[1];
    const float* v    = (const float*)d_in[2];
    const float* qcos = (const float*)d_in[3];
    const float* qsin = (const float*)d_in[4];
    const float* kcos = (const float*)d_in[5];
    const float* ksin = (const float*)d_in[6];
    const float* Wq   = (const float*)d_in[7];
    const float* bq   = (const float*)d_in[8];
    const float* Wk   = (const float*)d_in[9];
    const float* bk   = (const float*)d_in[10];
    const float* Wv   = (const float*)d_in[11];
    const float* bv   = (const float*)d_in[12];
    float* out = (float*)d_out;

    // workspace layout (bf16 buffers), total ~54 MB
    unsigned short* Xqb = (unsigned short*)d_ws;
    unsigned short* Xkb = Xqb + (size_t)MROWS * CDIM;
    unsigned short* Xvb = Xkb + (size_t)MROWS * CDIM;
    unsigned short* Wqb = Xvb + (size_t)MROWS * CDIM;
    unsigned short* Wkb = Wqb + (size_t)CDIM * CDIM;
    unsigned short* Wvb = Wkb + (size_t)CDIM * CDIM;
    unsigned short* Qhb = Wvb + (size_t)CDIM * CDIM;
    unsigned short* Khb = Qhb + (size_t)MROWS * CDIM;
    unsigned short* VTb = Khb + (size_t)MROWS * CDIM;

    const int nX = MROWS * CDIM;   // 4194304
    const int nW = CDIM * CDIM;    // 1048576
    cvt_bf16_kernel<<<nX / 1024, 256, 0, stream>>>(q, Xqb, nX);
    cvt_bf16_kernel<<<nX / 1024, 256, 0, stream>>>(k, Xkb, nX);
    cvt_bf16_kernel<<<nX / 1024, 256, 0, stream>>>(v, Xvb, nX);
    cvt_bf16_kernel<<<nW / 1024, 256, 0, stream>>>(Wq, Wqb, nW);
    cvt_bf16_kernel<<<nW / 1024, 256, 0, stream>>>(Wk, Wkb, nW);
    cvt_bf16_kernel<<<nW / 1024, 256, 0, stream>>>(Wv, Wvb, nW);

    dim3 gg(CDIM / 128, MROWS / 128, 3);   // (8, 32, 3)
    gemm_rope_kernel<<<gg, 256, 0, stream>>>(Xqb, Xkb, Xvb, Wqb, Wkb, Wvb,
                                             bq, bk, bv, qcos, qsin, kcos, ksin,
                                             Qhb, Khb, VTb);

    attn_kernel<<<dim3(NSEQ / 128, 2 * NHEAD), 256, 0, stream>>>(Qhb, Khb, VTb, out);
}

// Round 2
// 166.826 us; speedup vs baseline: 1.6117x; 1.6117x over previous
//
#include <hip/hip_runtime.h>
#include <hip/hip_bf16.h>

typedef float f32x4 __attribute__((ext_vector_type(4)));
typedef short bf16x8 __attribute__((ext_vector_type(8)));

#define NSEQ 2048
#define CDIM 1024
#define NHEAD 16
#define HDIM 64
#define MROWS 4096
// scale(1/8) * log2(e) folded into Q at projection epilogue
#define QSCALE 0.18033688011f
// defer-max threshold: 8 / ln(2) (P bounded by e^8)
#define DEFER_THR 11.5416f

__device__ __forceinline__ unsigned short f2bf(float f) {
    unsigned int u = __builtin_bit_cast(unsigned int, f);
    u += 0x7FFFu + ((u >> 16) & 1u);
    return (unsigned short)(u >> 16);
}

__device__ __forceinline__ void gload16(const void* g, void* l) {
    __builtin_amdgcn_global_load_lds(
        (const __attribute__((address_space(1))) unsigned int*)g,
        (__attribute__((address_space(3))) unsigned int*)l, 16, 0, 0);
}

// ---------------- all f32->bf16 conversions in ONE launch ----------------
__global__ __launch_bounds__(256) void cvt6_kernel(
    const float* __restrict__ q, const float* __restrict__ k, const float* __restrict__ v,
    const float* __restrict__ wq, const float* __restrict__ wk, const float* __restrict__ wv,
    unsigned short* __restrict__ dq, unsigned short* __restrict__ dk, unsigned short* __restrict__ dv,
    unsigned short* __restrict__ dwq, unsigned short* __restrict__ dwk, unsigned short* __restrict__ dwv)
{
    int b = blockIdx.x;
    const float* s; unsigned short* d; int base;
    if (b < 4096)       { s = q;  d = dq;  base = b; }
    else if (b < 8192)  { s = k;  d = dk;  base = b - 4096; }
    else if (b < 12288) { s = v;  d = dv;  base = b - 8192; }
    else if (b < 13312) { s = wq; d = dwq; base = b - 12288; }
    else if (b < 14336) { s = wk; d = dwk; base = b - 13312; }
    else                { s = wv; d = dwv; base = b - 14336; }
    int i = (base * 256 + threadIdx.x) * 4;
    float4 t4 = *reinterpret_cast<const float4*>(s + i);
    ushort4 o;
    o.x = f2bf(t4.x); o.y = f2bf(t4.y); o.z = f2bf(t4.z); o.w = f2bf(t4.w);
    *reinterpret_cast<ushort4*>(d + i) = o;
}

// ---------------- fused projection GEMM + bias + RoPE -------------------
// out[m,j] = sum_c X[m,c] * W[j,c] + b[j]; z=0:Q(rope,scaled) z=1:K(rope) z=2:V(->V^T)
__global__ __launch_bounds__(256) void gemm_rope_kernel(
    const unsigned short* __restrict__ Xq, const unsigned short* __restrict__ Xk,
    const unsigned short* __restrict__ Xv,
    const unsigned short* __restrict__ Wqb, const unsigned short* __restrict__ Wkb,
    const unsigned short* __restrict__ Wvb,
    const float* __restrict__ bq, const float* __restrict__ bk, const float* __restrict__ bv,
    const float* __restrict__ qcos, const float* __restrict__ qsin,
    const float* __restrict__ kcos, const float* __restrict__ ksin,
    unsigned short* __restrict__ Qh, unsigned short* __restrict__ Kh,
    unsigned short* __restrict__ VT)
{
    __shared__ unsigned short Al[128][72];
    __shared__ unsigned short Bl[128][72];

    const int tid  = threadIdx.x;
    const int wave = tid >> 6;
    const int lane = tid & 63;
    const int lr   = lane & 15;
    const int lg   = lane >> 4;
    const int lk   = lg * 8;
    const int wm   = wave >> 1;
    const int wn   = wave & 1;
    const int m0   = blockIdx.y * 128;
    const int j0   = blockIdx.x * 128;
    const int z    = blockIdx.z;

    const unsigned short* X = (z == 0) ? Xq : (z == 1) ? Xk : Xv;
    const unsigned short* W = (z == 0) ? Wqb : (z == 1) ? Wkb : Wvb;
    const float* bias = (z == 0) ? bq : (z == 1) ? bk : bv;
    const float* cosb = (z == 0) ? qcos : kcos;
    const float* sinb = (z == 0) ? qsin : ksin;

    f32x4 acc[4][4];
    const f32x4 zero4 = {0.f, 0.f, 0.f, 0.f};
    #pragma unroll
    for (int a = 0; a < 4; a++)
        #pragma unroll
        for (int b = 0; b < 4; b++) acc[a][b] = zero4;

    for (int k0 = 0; k0 < CDIM; k0 += 64) {
        __syncthreads();
        #pragma unroll
        for (int it = 0; it < 4; it++) {
            int c = tid + it * 256;
            int row = c >> 3, col = (c & 7) << 3;
            *reinterpret_cast<bf16x8*>(&Al[row][col]) =
                *reinterpret_cast<const bf16x8*>(X + (size_t)(m0 + row) * CDIM + k0 + col);
            *reinterpret_cast<bf16x8*>(&Bl[row][col]) =
                *reinterpret_cast<const bf16x8*>(W + (size_t)(j0 + row) * CDIM + k0 + col);
        }
        __syncthreads();
        #pragma unroll
        for (int ks = 0; ks < 2; ks++) {
            bf16x8 af[4], bfm[4];
            #pragma unroll
            for (int mi = 0; mi < 4; mi++)
                af[mi] = *reinterpret_cast<const bf16x8*>(&Al[wm * 64 + 16 * mi + lr][ks * 32 + lk]);
            #pragma unroll
            for (int ni = 0; ni < 4; ni++)
                bfm[ni] = *reinterpret_cast<const bf16x8*>(&Bl[wn * 64 + 16 * ni + lr][ks * 32 + lk]);
            #pragma unroll
            for (int mi = 0; mi < 4; mi++)
                #pragma unroll
                for (int ni = 0; ni < 4; ni++)
                    acc[mi][ni] = __builtin_amdgcn_mfma_f32_16x16x32_bf16(
                        af[mi], bfm[ni], acc[mi][ni], 0, 0, 0);
        }
    }

    #pragma unroll
    for (int mi = 0; mi < 4; mi++) {
        const int mbase = m0 + wm * 64 + 16 * mi + 4 * lg;
        #pragma unroll
        for (int ni = 0; ni < 4; ni++) {
            const int j  = j0 + wn * 64 + 16 * ni + lr;
            const float bj = bias[j];
            if (z == 2) {
                const int b = mbase >> 11, n = mbase & 2047;
                const int h = j >> 6, d = j & 63;
                ushort4 pk;
                pk.x = f2bf(acc[mi][ni][0] + bj);
                pk.y = f2bf(acc[mi][ni][1] + bj);
                pk.z = f2bf(acc[mi][ni][2] + bj);
                pk.w = f2bf(acc[mi][ni][3] + bj);
                *reinterpret_cast<ushort4*>(VT + ((size_t)((b * NHEAD + h) * HDIM + d) << 11) + n) = pk;
            } else {
                unsigned short* Out = (z == 0) ? Qh : Kh;
                const float scl = (z == 0) ? QSCALE : 1.0f;
                const int hi = (j & 63) >> 1;
                const float sg = (j & 1) ? 1.f : -1.f;
                float vv[4], pp[4];
                #pragma unroll
                for (int r = 0; r < 4; r++) vv[r] = acc[mi][ni][r] + bj;
                #pragma unroll
                for (int r = 0; r < 4; r++) pp[r] = __shfl_xor(vv[r], 1);
                #pragma unroll
                for (int r = 0; r < 4; r++) {
                    const int m = mbase + r;
                    const int b = m >> 11, n = m & 2047;
                    const float c = cosb[n * 32 + hi];
                    const float s = sinb[n * 32 + hi];
                    const float ov = fmaf(vv[r], c, pp[r] * (sg * s)) * scl;
                    Out[((size_t)((b * NHEAD + (j >> 6)) * NSEQ + n) << 6) + (j & 63)] = f2bf(ov);
                }
            }
        }
    }
}

// ---------------- flash attention (swapped QK^T, defer-max) -------------
// grid (32, 32): x = q-block of 64 rows, y = b*H+h. block 256 = 4 waves,
// wave owns 16 q-rows. KV tiles of 64, double-buffered via global_load_lds
// with XOR swizzle (linear dest + pre-swizzled src + swizzled read).
__global__ __launch_bounds__(256) void attn_kernel(
    const unsigned short* __restrict__ Qh, const unsigned short* __restrict__ Kh,
    const unsigned short* __restrict__ VT, float* __restrict__ out)
{
    __shared__ unsigned char Ksm[2][8192];   // [64 rows][128B], swizzled
    __shared__ unsigned char Vsm[2][8192];   // V^T tile [d][key], swizzled
    __shared__ unsigned char Psm[4][2304];   // per-wave P [16][72 bf16]

    const int tid  = threadIdx.x;
    const int wave = tid >> 6;
    const int lane = tid & 63;
    const int lr   = lane & 15;
    const int lg   = lane >> 4;
    const int bh   = blockIdx.y;
    const int q0w  = blockIdx.x * 64 + wave * 16;

    const unsigned short* Qb = Qh + (size_t)bh * NSEQ * HDIM;
    const char* Kb = (const char*)(Kh + (size_t)bh * NSEQ * HDIM);
    const char* Vb = (const char*)(VT + (size_t)bh * HDIM * NSEQ);

    // Q fragments (B-operand), held all kernel. Q already scaled by QSCALE.
    bf16x8 qf[2];
    #pragma unroll
    for (int ks = 0; ks < 2; ks++)
        qf[ks] = *reinterpret_cast<const bf16x8*>(
            Qb + (size_t)(q0w + lr) * HDIM + ks * 32 + lg * 8);

    const f32x4 zero4 = {0.f, 0.f, 0.f, 0.f};
    f32x4 o[4];
    #pragma unroll
    for (int ni = 0; ni < 4; ni++) o[ni] = zero4;
    float mrun = -1e30f, lrun = 0.f;

    // swizzled read column offsets (bytes) for K/V tiles
    const int swz = (lr & 7) << 4;
    const int co0 = (lg * 16) ^ swz;
    const int co1 = (64 + lg * 16) ^ swz;

    // staging constants: thread stages 2x16B of K and V each
    const int sr7 = lane >> 3;
    const int scb = ((lane & 7) * 16) ^ (sr7 << 4);
    const int ch0 = wave * 2;

    auto stage = [&](int buf, int n0) {
        #pragma unroll
        for (int i = 0; i < 2; ++i) {
            const int row = (ch0 + i) * 8 + sr7;
            gload16(Kb + (size_t)(n0 + row) * 128 + scb, &Ksm[buf][(ch0 + i) * 1024]);
            gload16(Vb + (size_t)row * (NSEQ * 2) + (size_t)n0 * 2 + scb,
                    &Vsm[buf][(ch0 + i) * 1024]);
        }
    };

    stage(0, 0);
    __syncthreads();
    int cur = 0;

    for (int t = 0; t < 32; ++t) {
        if (t < 31) stage(cur ^ 1, (t + 1) * 64);

        // S^T = mfma(K, Q): lane holds S(q=lr, key=16ni+4lg+r)
        f32x4 s[4];
        #pragma unroll
        for (int ni = 0; ni < 4; ni++) s[ni] = zero4;
        #pragma unroll
        for (int ks = 0; ks < 2; ks++) {
            const int co = ks ? co1 : co0;
            #pragma unroll
            for (int ni = 0; ni < 4; ni++) {
                bf16x8 kf = *reinterpret_cast<const bf16x8*>(
                    &Ksm[cur][(16 * ni + lr) * 128 + co]);
                s[ni] = __builtin_amdgcn_mfma_f32_16x16x32_bf16(kf, qf[ks], s[ni], 0, 0, 0);
            }
        }

        // row max: 15 in-lane + 2 shuffles (lanes lr,lr+16,lr+32,lr+48 share q-row)
        float tm = fmaxf(fmaxf(s[0][0], s[0][1]), fmaxf(s[0][2], s[0][3]));
        #pragma unroll
        for (int ni = 1; ni < 4; ni++)
            tm = fmaxf(tm, fmaxf(fmaxf(s[ni][0], s[ni][1]), fmaxf(s[ni][2], s[ni][3])));
        tm = fmaxf(tm, __shfl_xor(tm, 16));
        tm = fmaxf(tm, __shfl_xor(tm, 32));

        // defer-max: only rescale when some row max grew past threshold
        if (!__all(tm - mrun <= DEFER_THR)) {
            const float mnew  = fmaxf(mrun, tm);
            const float alpha = exp2f(mrun - mnew);
            mrun = mnew;
            lrun *= alpha;
            float afr[4];
            #pragma unroll
            for (int r = 0; r < 4; r++) afr[r] = __shfl(alpha, 4 * lg + r);
            #pragma unroll
            for (int ni = 0; ni < 4; ni++)
                #pragma unroll
                for (int r = 0; r < 4; r++) o[ni][r] *= afr[r];
        }

        float rs = 0.f;
        #pragma unroll
        for (int ni = 0; ni < 4; ni++)
            #pragma unroll
            for (int r = 0; r < 4; r++) {
                float p = exp2f(s[ni][r] - mrun);
                s[ni][r] = p;
                rs += p;
            }
        rs += __shfl_xor(rs, 16);
        rs += __shfl_xor(rs, 32);
        lrun += rs;

        // P -> LDS: key-contiguous packed writes (4x ds_write_b64)
        unsigned char* pbase = &Psm[wave][lr * 144 + lg * 8];
        #pragma unroll
        for (int ni = 0; ni < 4; ni++) {
            ushort4 pk;
            pk.x = f2bf(s[ni][0]); pk.y = f2bf(s[ni][1]);
            pk.z = f2bf(s[ni][2]); pk.w = f2bf(s[ni][3]);
            *reinterpret_cast<ushort4*>(pbase + 32 * ni) = pk;
        }

        // V fragments (independent of P writes — issue before the drain)
        bf16x8 vf[2][4];
        #pragma unroll
        for (int ks = 0; ks < 2; ks++) {
            const int co = ks ? co1 : co0;
            #pragma unroll
            for (int ni = 0; ni < 4; ni++)
                vf[ks][ni] = *reinterpret_cast<const bf16x8*>(
                    &Vsm[cur][(16 * ni + lr) * 128 + co]);
        }
        asm volatile("s_waitcnt lgkmcnt(0)" ::: "memory");

        const unsigned char* prow = &Psm[wave][lr * 144];
        bf16x8 pa[2];
        pa[0] = *reinterpret_cast<const bf16x8*>(prow + lg * 16);
        pa[1] = *reinterpret_cast<const bf16x8*>(prow + 64 + lg * 16);

        #pragma unroll
        for (int ks = 0; ks < 2; ks++)
            #pragma unroll
            for (int ni = 0; ni < 4; ni++)
                o[ni] = __builtin_amdgcn_mfma_f32_16x16x32_bf16(
                    pa[ks], vf[ks][ni], o[ni], 0, 0, 0);

        __syncthreads();
        cur ^= 1;
    }

    // epilogue: O(q=4lg+r, d=16ni+lr); l lives at lanes with lr==q
    float linv[4];
    #pragma unroll
    for (int r = 0; r < 4; r++) {
        float ll = __shfl(lrun, 4 * lg + r);
        linv[r] = 1.0f / ll;
    }
    const int b = bh >> 4, h = bh & 15;
    #pragma unroll
    for (int ni = 0; ni < 4; ni++)
        #pragma unroll
        for (int r = 0; r < 4; r++) {
            const int n = q0w + 4 * lg + r;
            out[((size_t)(b * NSEQ + n) << 10) + h * HDIM + 16 * ni + lr] =
                o[ni][r] * linv[r];
        }
}

extern "C" void kernel_launch(void* const* d_in, const int* in_sizes, int n_in,
                              void* d_out, int out_size, void* d_ws, size_t ws_size,
                              hipStream_t stream) {
    const float* q    = (const float*)d_in[0];
    const float* k    = (const float*)d_in[1];
    const float* v    = (const float*)d_in[2];
    const float* qcos = (const float*)d_in[3];
    const float* qsin = (const float*)d_in[4];
    const float* kcos = (const float*)d_in[5];
    const float* ksin = (const float*)d_in[6];
    const float* Wq   = (const float*)d_in[7];
    const float* bq   = (const float*)d_in[8];
    const float* Wk   = (const float*)d_in[9];
    const float* bk   = (const float*)d_in[10];
    const float* Wv   = (const float*)d_in[11];
    const float* bv   = (const float*)d_in[12];
    float* out = (float*)d_out;

    unsigned short* Xqb = (unsigned short*)d_ws;
    unsigned short* Xkb = Xqb + (size_t)MROWS * CDIM;
    unsigned short* Xvb = Xkb + (size_t)MROWS * CDIM;
    unsigned short* Wqb = Xvb + (size_t)MROWS * CDIM;
    unsigned short* Wkb = Wqb + (size_t)CDIM * CDIM;
    unsigned short* Wvb = Wkb + (size_t)CDIM * CDIM;
    unsigned short* Qhb = Wvb + (size_t)CDIM * CDIM;
    unsigned short* Khb = Qhb + (size_t)MROWS * CDIM;
    unsigned short* VTb = Khb + (size_t)MROWS * CDIM;

    cvt6_kernel<<<15360, 256, 0, stream>>>(q, k, v, Wq, Wk, Wv,
                                           Xqb, Xkb, Xvb, Wqb, Wkb, Wvb);

    dim3 gg(CDIM / 128, MROWS / 128, 3);
    gemm_rope_kernel<<<gg, 256, 0, stream>>>(Xqb, Xkb, Xvb, Wqb, Wkb, Wvb,
                                             bq, bk, bv, qcos, qsin, kcos, ksin,
                                             Qhb, Khb, VTb);

    attn_kernel<<<dim3(NSEQ / 64, 2 * NHEAD), 256, 0, stream>>>(Qhb, Khb, VTb, out);
}

// Round 3
// 137.578 us; speedup vs baseline: 1.9543x; 1.2126x over previous
//
#include <hip/hip_runtime.h>
#include <hip/hip_bf16.h>

typedef float f32x4 __attribute__((ext_vector_type(4)));
typedef float f32x16 __attribute__((ext_vector_type(16)));
typedef short bf16x8 __attribute__((ext_vector_type(8)));

#define NSEQ 2048
#define CDIM 1024
#define NHEAD 16
#define HDIM 64
#define MROWS 4096
// scale(1/8) * log2(e) folded into Q at projection epilogue
#define QSCALE 0.18033688011f
// defer-max threshold: 8 / ln(2) (P bounded by e^8)
#define DEFER_THR 11.5416f

__device__ __forceinline__ unsigned short f2bf(float f) {
    unsigned int u = __builtin_bit_cast(unsigned int, f);
    u += 0x7FFFu + ((u >> 16) & 1u);
    return (unsigned short)(u >> 16);
}

__device__ __forceinline__ unsigned pkbf(float lo, float hi_) {
    unsigned r;
    asm("v_cvt_pk_bf16_f32 %0, %1, %2" : "=v"(r) : "v"(lo), "v"(hi_));
    return r;
}

__device__ __forceinline__ void gload16(const void* g, void* l) {
    __builtin_amdgcn_global_load_lds(
        (const __attribute__((address_space(1))) unsigned int*)g,
        (__attribute__((address_space(3))) unsigned int*)l, 16, 0, 0);
}

// ---------------- all f32->bf16 conversions in ONE launch ----------------
__global__ __launch_bounds__(256) void cvt6_kernel(
    const float* __restrict__ q, const float* __restrict__ k, const float* __restrict__ v,
    const float* __restrict__ wq, const float* __restrict__ wk, const float* __restrict__ wv,
    unsigned short* __restrict__ dq, unsigned short* __restrict__ dk, unsigned short* __restrict__ dv,
    unsigned short* __restrict__ dwq, unsigned short* __restrict__ dwk, unsigned short* __restrict__ dwv)
{
    int b = blockIdx.x;
    const float* s; unsigned short* d; int base;
    if (b < 4096)       { s = q;  d = dq;  base = b; }
    else if (b < 8192)  { s = k;  d = dk;  base = b - 4096; }
    else if (b < 12288) { s = v;  d = dv;  base = b - 8192; }
    else if (b < 13312) { s = wq; d = dwq; base = b - 12288; }
    else if (b < 14336) { s = wk; d = dwk; base = b - 13312; }
    else                { s = wv; d = dwv; base = b - 14336; }
    int i = (base * 256 + threadIdx.x) * 4;
    float4 t4 = *reinterpret_cast<const float4*>(s + i);
    ushort4 o;
    o.x = f2bf(t4.x); o.y = f2bf(t4.y); o.z = f2bf(t4.z); o.w = f2bf(t4.w);
    *reinterpret_cast<ushort4*>(d + i) = o;
}

// ---------------- fused projection GEMM + bias + RoPE -------------------
__global__ __launch_bounds__(256) void gemm_rope_kernel(
    const unsigned short* __restrict__ Xq, const unsigned short* __restrict__ Xk,
    const unsigned short* __restrict__ Xv,
    const unsigned short* __restrict__ Wqb, const unsigned short* __restrict__ Wkb,
    const unsigned short* __restrict__ Wvb,
    const float* __restrict__ bq, const float* __restrict__ bk, const float* __restrict__ bv,
    const float* __restrict__ qcos, const float* __restrict__ qsin,
    const float* __restrict__ kcos, const float* __restrict__ ksin,
    unsigned short* __restrict__ Qh, unsigned short* __restrict__ Kh,
    unsigned short* __restrict__ VT)
{
    __shared__ unsigned short Al[128][72];
    __shared__ unsigned short Bl[128][72];

    const int tid  = threadIdx.x;
    const int wave = tid >> 6;
    const int lane = tid & 63;
    const int lr   = lane & 15;
    const int lg   = lane >> 4;
    const int lk   = lg * 8;
    const int wm   = wave >> 1;
    const int wn   = wave & 1;
    const int m0   = blockIdx.y * 128;
    const int j0   = blockIdx.x * 128;
    const int z    = blockIdx.z;

    const unsigned short* X = (z == 0) ? Xq : (z == 1) ? Xk : Xv;
    const unsigned short* W = (z == 0) ? Wqb : (z == 1) ? Wkb : Wvb;
    const float* bias = (z == 0) ? bq : (z == 1) ? bk : bv;
    const float* cosb = (z == 0) ? qcos : kcos;
    const float* sinb = (z == 0) ? qsin : ksin;

    f32x4 acc[4][4];
    const f32x4 zero4 = {0.f, 0.f, 0.f, 0.f};
    #pragma unroll
    for (int a = 0; a < 4; a++)
        #pragma unroll
        for (int b = 0; b < 4; b++) acc[a][b] = zero4;

    for (int k0 = 0; k0 < CDIM; k0 += 64) {
        __syncthreads();
        #pragma unroll
        for (int it = 0; it < 4; it++) {
            int c = tid + it * 256;
            int row = c >> 3, col = (c & 7) << 3;
            *reinterpret_cast<bf16x8*>(&Al[row][col]) =
                *reinterpret_cast<const bf16x8*>(X + (size_t)(m0 + row) * CDIM + k0 + col);
            *reinterpret_cast<bf16x8*>(&Bl[row][col]) =
                *reinterpret_cast<const bf16x8*>(W + (size_t)(j0 + row) * CDIM + k0 + col);
        }
        __syncthreads();
        #pragma unroll
        for (int ks = 0; ks < 2; ks++) {
            bf16x8 af[4], bfm[4];
            #pragma unroll
            for (int mi = 0; mi < 4; mi++)
                af[mi] = *reinterpret_cast<const bf16x8*>(&Al[wm * 64 + 16 * mi + lr][ks * 32 + lk]);
            #pragma unroll
            for (int ni = 0; ni < 4; ni++)
                bfm[ni] = *reinterpret_cast<const bf16x8*>(&Bl[wn * 64 + 16 * ni + lr][ks * 32 + lk]);
            #pragma unroll
            for (int mi = 0; mi < 4; mi++)
                #pragma unroll
                for (int ni = 0; ni < 4; ni++)
                    acc[mi][ni] = __builtin_amdgcn_mfma_f32_16x16x32_bf16(
                        af[mi], bfm[ni], acc[mi][ni], 0, 0, 0);
        }
    }

    #pragma unroll
    for (int mi = 0; mi < 4; mi++) {
        const int mbase = m0 + wm * 64 + 16 * mi + 4 * lg;
        #pragma unroll
        for (int ni = 0; ni < 4; ni++) {
            const int j  = j0 + wn * 64 + 16 * ni + lr;
            const float bj = bias[j];
            if (z == 2) {
                const int b = mbase >> 11, n = mbase & 2047;
                const int h = j >> 6, d = j & 63;
                ushort4 pk;
                pk.x = f2bf(acc[mi][ni][0] + bj);
                pk.y = f2bf(acc[mi][ni][1] + bj);
                pk.z = f2bf(acc[mi][ni][2] + bj);
                pk.w = f2bf(acc[mi][ni][3] + bj);
                *reinterpret_cast<ushort4*>(VT + ((size_t)((b * NHEAD + h) * HDIM + d) << 11) + n) = pk;
            } else {
                unsigned short* Out = (z == 0) ? Qh : Kh;
                const float scl = (z == 0) ? QSCALE : 1.0f;
                const int hi = (j & 63) >> 1;
                const float sg = (j & 1) ? 1.f : -1.f;
                float vv[4], pp[4];
                #pragma unroll
                for (int r = 0; r < 4; r++) vv[r] = acc[mi][ni][r] + bj;
                #pragma unroll
                for (int r = 0; r < 4; r++) pp[r] = __shfl_xor(vv[r], 1);
                #pragma unroll
                for (int r = 0; r < 4; r++) {
                    const int m = mbase + r;
                    const int b = m >> 11, n = m & 2047;
                    const float c = cosb[n * 32 + hi];
                    const float s = sinb[n * 32 + hi];
                    const float ov = fmaf(vv[r], c, pp[r] * (sg * s)) * scl;
                    Out[((size_t)((b * NHEAD + (j >> 6)) * NSEQ + n) << 6) + (j & 63)] = f2bf(ov);
                }
            }
        }
    }
}

// ---------------- flash attention: 32x32 MFMA, in-register softmax -------
// grid (16, 32): x = q-block of 128 rows, y = b*H+h. block 256 = 4 waves,
// wave owns 32 q-rows. Swapped QK^T: S^T = mfma(K, Q) -> lane holds full
// P-row (32 of 64 keys; partner lane^32 has the rest). KV tiles of 64,
// double-buffered global_load_lds with row-XOR swizzle.
__global__ __launch_bounds__(256, 2) void attn_kernel(
    const unsigned short* __restrict__ Qh, const unsigned short* __restrict__ Kh,
    const unsigned short* __restrict__ VT, float* __restrict__ out)
{
    __shared__ unsigned char Ksm[2][8192];   // [64 keys][128B d], swizzled
    __shared__ unsigned char Vsm[2][8192];   // [64 d][128B keys], swizzled

    const int tid  = threadIdx.x;
    const int wave = tid >> 6;
    const int lane = tid & 63;
    const int c    = lane & 31;
    const int hi   = lane >> 5;
    const int bh   = blockIdx.y;
    const int q0w  = blockIdx.x * 128 + wave * 32;
    const int sw   = (c & 7) << 4;           // read-side XOR swizzle

    const unsigned short* Qb = Qh + (size_t)bh * NSEQ * HDIM;
    const char* Kb = (const char*)(Kh + (size_t)bh * NSEQ * HDIM);
    const char* Vb = (const char*)(VT + (size_t)bh * HDIM * NSEQ);

    // Q as B-operand: lane holds Q[d = 16s+8hi+j][q = q0w+c]
    bf16x8 qf[4];
    #pragma unroll
    for (int s = 0; s < 4; s++)
        qf[s] = *reinterpret_cast<const bf16x8*>(
            Qb + (size_t)(q0w + c) * HDIM + s * 16 + hi * 8);

    const f32x16 z16 = {0,0,0,0,0,0,0,0,0,0,0,0,0,0,0,0};
    f32x16 o0 = z16, o1 = z16;
    float mrun = -1e30f, lrun = 0.f;

    // staging: thread stages 2x16B of K and V each (pre-swizzled source)
    const int sr7 = lane >> 3;
    const int scb = ((lane & 7) * 16) ^ (sr7 << 4);
    const int ch0 = wave * 2;

    auto stage = [&](int buf, int n0) {
        #pragma unroll
        for (int i = 0; i < 2; ++i) {
            const int row = (ch0 + i) * 8 + sr7;
            gload16(Kb + (size_t)(n0 + row) * 128 + scb, &Ksm[buf][(ch0 + i) * 1024]);
            gload16(Vb + (size_t)row * (NSEQ * 2) + (size_t)n0 * 2 + scb,
                    &Vsm[buf][(ch0 + i) * 1024]);
        }
    };

    stage(0, 0);
    __syncthreads();
    int cur = 0;

    for (int t = 0; t < 32; ++t) {
        if (t < 31) stage(cur ^ 1, (t + 1) * 64);

        // S^T tiles: s0 = keys 0..31, s1 = keys 32..63 (cols = q)
        f32x16 s0 = z16, s1 = z16;
        #pragma unroll
        for (int s = 0; s < 4; s++) {
            const int cb = (32 * s + 16 * hi) ^ sw;
            bf16x8 kf0 = *reinterpret_cast<const bf16x8*>(&Ksm[cur][c * 128 + cb]);
            bf16x8 kf1 = *reinterpret_cast<const bf16x8*>(&Ksm[cur][(32 + c) * 128 + cb]);
            s0 = __builtin_amdgcn_mfma_f32_32x32x16_bf16(kf0, qf[s], s0, 0, 0, 0);
            s1 = __builtin_amdgcn_mfma_f32_32x32x16_bf16(kf1, qf[s], s1, 0, 0, 0);
        }

        // row max: 31 in-lane + 1 partner exchange (lane^32 holds other keys)
        float tmx[8];
        #pragma unroll
        for (int i = 0; i < 8; i++)
            tmx[i] = fmaxf(fmaxf(s0[2 * i], s0[2 * i + 1]),
                           fmaxf(s1[2 * i], s1[2 * i + 1]));
        float tm = fmaxf(fmaxf(fmaxf(tmx[0], tmx[1]), fmaxf(tmx[2], tmx[3])),
                         fmaxf(fmaxf(tmx[4], tmx[5]), fmaxf(tmx[6], tmx[7])));
        tm = fmaxf(tm, __shfl_xor(tm, 32));

        // defer-max: rescale only when a row max grew past threshold
        if (!__all(tm - mrun <= DEFER_THR)) {
            const float mnew  = fmaxf(mrun, tm);
            const float alpha = exp2f(mrun - mnew);
            mrun = mnew;
            lrun *= alpha;
            #pragma unroll
            for (int r = 0; r < 16; r++) {
                const float ar = __shfl(alpha, (r & 3) + 8 * (r >> 2) + 4 * hi);
                o0[r] *= ar;
                o1[r] *= ar;
            }
        }

        // P = exp2(S - m), row sum
        #pragma unroll
        for (int r = 0; r < 16; r++) s0[r] = exp2f(s0[r] - mrun);
        #pragma unroll
        for (int r = 0; r < 16; r++) s1[r] = exp2f(s1[r] - mrun);
        float rsx[8];
        #pragma unroll
        for (int i = 0; i < 8; i++)
            rsx[i] = (s0[2 * i] + s0[2 * i + 1]) + (s1[2 * i] + s1[2 * i + 1]);
        float rs = ((rsx[0] + rsx[1]) + (rsx[2] + rsx[3])) +
                   ((rsx[4] + rsx[5]) + (rsx[6] + rsx[7]));
        rs += __shfl_xor(rs, 32);
        lrun += rs;

        // P -> A-fragments in-register: cvt_pk pairs + permlane32_swap
        unsigned pw[4][4];
        #pragma unroll
        for (int u = 0; u < 4; u++) {
            const f32x16& sv = (u < 2) ? s0 : s1;
            const int b = (u & 1) * 8;
            unsigned x0 = pkbf(sv[b + 0], sv[b + 1]);
            unsigned y0 = pkbf(sv[b + 4], sv[b + 5]);
            asm("v_permlane32_swap_b32 %0, %1" : "+v"(x0), "+v"(y0));
            unsigned x1 = pkbf(sv[b + 2], sv[b + 3]);
            unsigned y1 = pkbf(sv[b + 6], sv[b + 7]);
            asm("v_permlane32_swap_b32 %0, %1" : "+v"(x1), "+v"(y1));
            pw[u][0] = x0; pw[u][1] = x1; pw[u][2] = y0; pw[u][3] = y1;
        }

        // O += P V  (o0: d 0..31, o1: d 32..63)
        #pragma unroll
        for (int u = 0; u < 4; u++) {
            uint4 w;
            w.x = pw[u][0]; w.y = pw[u][1]; w.z = pw[u][2]; w.w = pw[u][3];
            bf16x8 pa = __builtin_bit_cast(bf16x8, w);
            const int cb = (32 * u + 16 * hi) ^ sw;
            bf16x8 vf0 = *reinterpret_cast<const bf16x8*>(&Vsm[cur][c * 128 + cb]);
            bf16x8 vf1 = *reinterpret_cast<const bf16x8*>(&Vsm[cur][(32 + c) * 128 + cb]);
            o0 = __builtin_amdgcn_mfma_f32_32x32x16_bf16(pa, vf0, o0, 0, 0, 0);
            o1 = __builtin_amdgcn_mfma_f32_32x32x16_bf16(pa, vf1, o1, 0, 0, 0);
        }

        __syncthreads();
        cur ^= 1;
    }

    // epilogue: normalize rows, write [B,N,C] f32
    const int b = bh >> 4, h = bh & 15;
    #pragma unroll
    for (int r = 0; r < 16; r++) {
        const int qrow = (r & 3) + 8 * (r >> 2) + 4 * hi;
        const float li  = __shfl(lrun, qrow);
        const float inv = 1.0f / li;
        const int n = q0w + qrow;
        float* op = out + ((size_t)(b * NSEQ + n) << 10) + h * HDIM + c;
        op[0]  = o0[r] * inv;
        op[32] = o1[r] * inv;
    }
}

extern "C" void kernel_launch(void* const* d_in, const int* in_sizes, int n_in,
                              void* d_out, int out_size, void* d_ws, size_t ws_size,
                              hipStream_t stream) {
    const float* q    = (const float*)d_in[0];
    const float* k    = (const float*)d_in[1];
    const float* v    = (const float*)d_in[2];
    const float* qcos = (const float*)d_in[3];
    const float* qsin = (const float*)d_in[4];
    const float* kcos = (const float*)d_in[5];
    const float* ksin = (const float*)d_in[6];
    const float* Wq   = (const float*)d_in[7];
    const float* bq   = (const float*)d_in[8];
    const float* Wk   = (const float*)d_in[9];
    const float* bk   = (const float*)d_in[10];
    const float* Wv   = (const float*)d_in[11];
    const float* bv   = (const float*)d_in[12];
    float* out = (float*)d_out;

    unsigned short* Xqb = (unsigned short*)d_ws;
    unsigned short* Xkb = Xqb + (size_t)MROWS * CDIM;
    unsigned short* Xvb = Xkb + (size_t)MROWS * CDIM;
    unsigned short* Wqb = Xvb + (size_t)MROWS * CDIM;
    unsigned short* Wkb = Wqb + (size_t)CDIM * CDIM;
    unsigned short* Wvb = Wkb + (size_t)CDIM * CDIM;
    unsigned short* Qhb = Wvb + (size_t)CDIM * CDIM;
    unsigned short* Khb = Qhb + (size_t)MROWS * CDIM;
    unsigned short* VTb = Khb + (size_t)MROWS * CDIM;

    cvt6_kernel<<<15360, 256, 0, stream>>>(q, k, v, Wq, Wk, Wv,
                                           Xqb, Xkb, Xvb, Wqb, Wkb, Wvb);

    dim3 gg(CDIM / 128, MROWS / 128, 3);
    gemm_rope_kernel<<<gg, 256, 0, stream>>>(Xqb, Xkb, Xvb, Wqb, Wkb, Wvb,
                                             bq, bk, bv, qcos, qsin, kcos, ksin,
                                             Qhb, Khb, VTb);

    attn_kernel<<<dim3(NSEQ / 128, 2 * NHEAD), 256, 0, stream>>>(Qhb, Khb, VTb, out);
}